// Round 16
// baseline (1149.844 us; speedup 1.0000x reference)
//
#include <hip/hip_runtime.h>
#include <hip/hip_bf16.h>

typedef __attribute__((ext_vector_type(8))) short bf16x8;
typedef __attribute__((ext_vector_type(4))) float f32x4;
typedef __attribute__((ext_vector_type(4))) int   i32x4;
typedef signed char i8;

#define N_ROWS 32768
#define K_KEYS 4096
#define DDIM   1024
#define BM 32
#define BK 128
#define NBLK (K_KEYS / BK)   /* 32 */
#define NT_TOT (NBLK * 8)    /* 256 key-tiles of 16 */
#define SP 132               /* Sx u32 pitch */
#define SC2 (1.52587890625e-05f) /* 2^-16 */

__device__ __forceinline__ ushort f2bf(float f) {
    __hip_bfloat16 b = __float2bfloat16(f);
    return *(ushort*)&b;
}
__device__ __forceinline__ float bf2f(ushort u) {
    __hip_bfloat16 b = *(__hip_bfloat16*)&u;
    return __bfloat162float(b);
}
__device__ __forceinline__ int clampi(int x) { return x > 127 ? 127 : (x < -127 ? -127 : x); }

// Pt swizzle (ushort units, 8-ushort granule XORed with row&7)
__device__ __forceinline__ int pidx(int r, int c_us) { return r * 128 + (c_us ^ ((r & 7) << 3)); }

// barrier that does NOT drain vmcnt: global prefetches stay in flight.
__device__ __forceinline__ void barrier_lgkm() {
    asm volatile("s_waitcnt lgkmcnt(0)" ::: "memory");
    __builtin_amdgcn_s_barrier();
    asm volatile("" ::: "memory");
}

// ---- prep: keys -> single K stream: [KL,KH] interleaved, tiles (g,m)=16 keys x 32 dims ----
__global__ void prep_kb(const float* __restrict__ keys, i8* __restrict__ sb) {
    int idx  = blockIdx.x * 256 + threadIdx.x;
    int lane = idx & 63, tile = idx >> 6;        // tile = g*32 + m
    int g = tile >> 5, m = tile & 31;
    int key = g * 16 + (lane & 15);
    int d0  = m * 32 + (lane >> 4) * 8;
    const float* s = keys + (size_t)key * DDIM + d0;
    union { i32x4 v; i8 b[16]; } u;
#pragma unroll
    for (int e = 0; e < 8; e++) {
        float q = s[e];
        int h = clampi((int)rintf(q * 16.f));
        int l = clampi((int)rintf((q - (float)h * 0.0625f) * 4096.f));
        u.b[2 * e]     = (i8)l;   // KL pairs with QH
        u.b[2 * e + 1] = (i8)h;   // KH pairs with QL / masked-QH
    }
    *(i32x4*)(sb + (size_t)tile * 1024 + lane * 16) = u.v;
}

// ---- prep: values fp32 [K][D] -> packed V^T bf16 fragment tiles ----
__global__ void prep_vt(const float* __restrict__ v, ushort* __restrict__ vt) {
    __shared__ float t[32][33];
    const int tk = blockIdx.x;
    const int td = blockIdx.y;
    const int tx = threadIdx.x & 31;
    const int ty = threadIdx.x >> 5;
#pragma unroll
    for (int r = 0; r < 4; r++) {
        int k = tk * 32 + ty + 8 * r;
        t[ty + 8 * r][tx] = v[(size_t)k * DDIM + td * 32 + tx];
    }
    __syncthreads();
    if (threadIdx.x < 128) {
        int s    = threadIdx.x >> 6;
        int lane = threadIdx.x & 63;
        int l16  = lane & 15, lq = lane >> 4;
        int dg   = td * 2 + s;
        int dl   = s * 16 + l16;
        bf16x8 o;
#pragma unroll
        for (int e = 0; e < 8; e++)
            o[e] = (short)f2bf(t[lq * 8 + e][dl]);
        *(bf16x8*)(vt + ((size_t)dg * 128 + tk) * 512 + lane * 8) = o;
    }
}

// Fused flash kernel, 16-WAVE version (1024 threads/block), round-15 base +
//  1. kB DISTANCE-2 via same-buffer rotation (consume kB[cb], reload it with
//     tile t+2) — ZERO extra registers; attacks the ~300cy/gt L3-latency
//     stall (16MB sb+vt working set misses the 4MB per-XCD L2).
//  2. PV pa0/pa1 staggered (one pa live at a time, -8 peak regs, shaves
//     the ~90MB residual spill).
__launch_bounds__(1024, 4)
__global__ void attn_main(const float* __restrict__ z,
                          const i8* __restrict__ sb,
                          const ushort* __restrict__ vtp,
                          float* __restrict__ out) {
    __shared__ unsigned Sx[BM][SP];       // 16896 B, fixed-point 2^-16
    __shared__ ushort Pt2[2][BM * 128];   // 16384 B
    __shared__ float  m_s[BM], l_s[BM], sc_s[BM];

    const int tid  = threadIdx.x;
    const int wave = tid >> 6;            // 0..15
    const int lane = tid & 63;
    const int l16  = lane & 15;
    const int lq   = lane >> 4;
    const int row0 = blockIdx.x * BM;

    // ---- Q fragments for this wave's 64 dims, in registers ----
    // qM2[rg][m]:  even byte QH, odd byte QL  (cross terms vs [KL,KH])
    // qP1z[rg][m]: even byte 0,  odd byte QH  (P1 = sum QH*KH, exact)
    i32x4 qM2[2][2], qP1z[2][2];
#pragma unroll
    for (int rg = 0; rg < 2; rg++) {
        int row = row0 + rg * 16 + l16;
        const float* zr = z + (size_t)row * DDIM + wave * 64;
#pragma unroll
        for (int m = 0; m < 2; m++) {
            union { i32x4 v; i8 b[16]; } u, w;
            const float* s = zr + m * 32 + lq * 8;
#pragma unroll
            for (int e = 0; e < 8; e++) {
                float q = s[e];
                int h = clampi((int)rintf(q * 16.f));
                int l = clampi((int)rintf((q - (float)h * 0.0625f) * 4096.f));
                u.b[2 * e]     = (i8)h;
                u.b[2 * e + 1] = (i8)l;
                w.b[2 * e]     = 0;
                w.b[2 * e + 1] = (i8)h;
            }
            qM2[rg][m]  = u.v;
            qP1z[rg][m] = w.v;
        }
    }
    if (tid < BM) { m_s[tid] = -1e30f; l_s[tid] = 0.f; }
    for (int i = tid; i < BM * SP; i += 1024)
        ((unsigned*)Sx)[i] = 0u;
    __syncthreads();

    f32x4 Oacc[2][4];
#pragma unroll
    for (int mt = 0; mt < 2; mt++)
#pragma unroll
        for (int nt = 0; nt < 4; nt++)
            Oacc[mt][nt] = (f32x4){0.f, 0.f, 0.f, 0.f};

    // K stream: wave uses m-slices {2w, 2w+1} of each 16-key tile g
    const i8* sbB = sb + (size_t)wave * 2048 + lane * 16;
    // vt: wave owns dg = 4w..4w+3 (nt=0..3)
    const ushort* vtB = vtp + (size_t)wave * 262144 + lane * 8;

    i32x4 kB[2][2];
#define LOADKB(gg, buf)                                                        \
    do {                                                                       \
        const i8* _b = sbB + (size_t)(gg) * 32768;                             \
        kB[buf][0] = *(const i32x4*)_b;                                        \
        kB[buf][1] = *(const i32x4*)(_b + 1024);                               \
    } while (0)

    // distance-2 prologue: tiles 0,1 in flight (tile t lives in buffer t&1)
    LOADKB(0, 0);
    LOADKB(1, 1);

    for (int b = 0; b < NBLK; b++) {
        // ---- QK^T: per key-tile gt (16 keys), 8 int8 MFMAs over 64 dims ----
#pragma unroll
        for (int gt = 0; gt < 8; gt++) {
            const int cb = gt & 1;
            i32x4 p1a = {0,0,0,0}, p1b = {0,0,0,0};
            i32x4 m2a = {0,0,0,0}, m2b = {0,0,0,0};
            // m = 0
            m2a = __builtin_amdgcn_mfma_i32_16x16x64_i8(qM2[0][0],  kB[cb][0], m2a, 0, 0, 0);
            m2b = __builtin_amdgcn_mfma_i32_16x16x64_i8(qM2[1][0],  kB[cb][0], m2b, 0, 0, 0);
            p1a = __builtin_amdgcn_mfma_i32_16x16x64_i8(qP1z[0][0], kB[cb][0], p1a, 0, 0, 0);
            p1b = __builtin_amdgcn_mfma_i32_16x16x64_i8(qP1z[1][0], kB[cb][0], p1b, 0, 0, 0);
            // m = 1
            m2a = __builtin_amdgcn_mfma_i32_16x16x64_i8(qM2[0][1],  kB[cb][1], m2a, 0, 0, 0);
            m2b = __builtin_amdgcn_mfma_i32_16x16x64_i8(qM2[1][1],  kB[cb][1], m2b, 0, 0, 0);
            p1a = __builtin_amdgcn_mfma_i32_16x16x64_i8(qP1z[0][1], kB[cb][1], p1a, 0, 0, 0);
            p1b = __builtin_amdgcn_mfma_i32_16x16x64_i8(qP1z[1][1], kB[cb][1], p1b, 0, 0, 0);

            // distance-2 rotation: reload this buffer with tile t+2
            // (WAR on kB[cb] is safe: MFMAs above read operands at issue)
            {
                int tn = 8 * b + gt + 2;
                if (tn > NT_TOT - 1) tn = NT_TOT - 1;
                LOADKB(tn, cb);
            }

            const int col = gt * 16 + l16;
#pragma unroll
            for (int r = 0; r < 4; r++) {
                int fa = p1a[r] * 256 + m2a[r];
                int fb = p1b[r] * 256 + m2b[r];
                atomicAdd(&Sx[lq * 4 + r][col],      (unsigned)fa);
                atomicAdd(&Sx[16 + lq * 4 + r][col], (unsigned)fb);
            }
        }

        // vt kc=0 prefetch (single buffer): lands during softmax
        bf16x8 vbuf[4];
        const ushort* vtI = vtB + (size_t)b * 2048;
#pragma unroll
        for (int nt = 0; nt < 4; nt++)
            vbuf[nt] = *(const bf16x8*)(vtI + nt * 65536);

        barrier_lgkm();

        // ---- softmax: thread (row, c0) owns cols [4c0, 4c0+4), 32 threads/row ----
        {
            const int row = tid >> 5;
            const int c0  = tid & 31;
            i32x4 w0 = *(const i32x4*)&Sx[row][4 * c0];
            *(i32x4*)&Sx[row][4 * c0] = (i32x4){0,0,0,0};   // zero for next iter
            float sv[4];
#pragma unroll
            for (int j = 0; j < 4; j++)
                sv[j] = (float)w0[j] * SC2;
            float mloc = fmaxf(fmaxf(sv[0], sv[1]), fmaxf(sv[2], sv[3]));
#pragma unroll
            for (int off = 16; off >= 1; off >>= 1)
                mloc = fmaxf(mloc, __shfl_xor(mloc, off));
            float m_old = m_s[row];
            float m_new = fmaxf(m_old, mloc);
            float psum = 0.f;
            ushort pb[4];
#pragma unroll
            for (int j = 0; j < 4; j++) {
                float p = __expf(sv[j] - m_new);
                psum += p;
                pb[j] = f2bf(p);
            }
            *(ushort4*)&Pt2[b & 1][pidx(row, 4 * c0)] = make_ushort4(pb[0], pb[1], pb[2], pb[3]);
#pragma unroll
            for (int off = 16; off >= 1; off >>= 1)
                psum += __shfl_xor(psum, off);
            if (c0 == 0) {
                float sc = __expf(m_old - m_new);
                l_s[row] = l_s[row] * sc + psum;
                m_s[row] = m_new;
                sc_s[row] = sc;
            }
        }
        barrier_lgkm();

        // ---- rescale O (exact skip when all sc==1), then PV ----
        {
            float sc0[4], sc1[4];
#pragma unroll
            for (int r = 0; r < 4; r++) {
                sc0[r] = sc_s[lq * 4 + r];
                sc1[r] = sc_s[16 + lq * 4 + r];
            }
            bool need = (sc0[0] != 1.f) || (sc0[1] != 1.f) || (sc0[2] != 1.f) || (sc0[3] != 1.f) ||
                        (sc1[0] != 1.f) || (sc1[1] != 1.f) || (sc1[2] != 1.f) || (sc1[3] != 1.f);
            if (__any(need)) {
#pragma unroll
                for (int nt = 0; nt < 4; nt++)
#pragma unroll
                    for (int r = 0; r < 4; r++) {
                        Oacc[0][nt][r] *= sc0[r];
                        Oacc[1][nt][r] *= sc1[r];
                    }
            }
        }

        const ushort* PtC = &Pt2[b & 1][0];
#pragma unroll
        for (int kc = 0; kc < 4; kc++) {
            // staggered: pa0 then pa1 (one pa live at a time)
            {
                bf16x8 pa0 = *(const bf16x8*)&PtC[pidx(l16, kc * 32 + lq * 8)];
#pragma unroll
                for (int nt = 0; nt < 4; nt++)
                    Oacc[0][nt] = __builtin_amdgcn_mfma_f32_16x16x32_bf16(pa0, vbuf[nt], Oacc[0][nt], 0, 0, 0);
            }
            {
                bf16x8 pa1 = *(const bf16x8*)&PtC[pidx(16 + l16, kc * 32 + lq * 8)];
#pragma unroll
                for (int nt = 0; nt < 4; nt++)
                    Oacc[1][nt] = __builtin_amdgcn_mfma_f32_16x16x32_bf16(pa1, vbuf[nt], Oacc[1][nt], 0, 0, 0);
            }
            // sequential reload of the single buffer with kc+1 (after MFMAs issue)
            if (kc < 3) {
#pragma unroll
                for (int nt = 0; nt < 4; nt++)
                    vbuf[nt] = *(const bf16x8*)(vtI + nt * 65536 + (kc + 1) * 512);
            }
        }
    }
    __syncthreads();

    // ---- epilogue: normalize by l and store ----
    float li0[4], li1[4];
#pragma unroll
    for (int r = 0; r < 4; r++) {
        li0[r] = 1.f / l_s[lq * 4 + r];
        li1[r] = 1.f / l_s[16 + lq * 4 + r];
    }
#pragma unroll
    for (int nt = 0; nt < 4; nt++) {
#pragma unroll
        for (int r = 0; r < 4; r++) {
            int col = wave * 64 + nt * 16 + l16;
            int rowA = row0 + lq * 4 + r;
            out[(size_t)rowA * DDIM + col]        = Oacc[0][nt][r] * li0[r];
            out[(size_t)(rowA + 16) * DDIM + col] = Oacc[1][nt][r] * li1[r];
        }
    }
}

extern "C" void kernel_launch(void* const* d_in, const int* in_sizes, int n_in,
                              void* d_out, int out_size, void* d_ws, size_t ws_size,
                              hipStream_t stream) {
    const float* z    = (const float*)d_in[0];
    const float* keys = (const float*)d_in[1];
    const float* vals = (const float*)d_in[2];
    float* outp = (float*)d_out;

    i8* sb = (i8*)d_ws;                                    // 8 MB (merged [KL,KH] tiles)
    ushort* vtw = (ushort*)(sb + (size_t)8 * 1024 * 1024); // 8 MB (V^T bf16 tiles)

    prep_kb<<<2048, 256, 0, stream>>>(keys, sb);
    prep_vt<<<dim3(K_KEYS / 32, DDIM / 32), 256, 0, stream>>>(vals, vtw);
    attn_main<<<N_ROWS / BM, 1024, 0, stream>>>(z, sb, vtw, outp);
}

// Round 17
// 928.883 us; speedup vs baseline: 1.2379x; 1.2379x over previous
//
#include <hip/hip_runtime.h>
#include <hip/hip_bf16.h>

typedef __attribute__((ext_vector_type(8))) short bf16x8;
typedef __attribute__((ext_vector_type(4))) float f32x4;
typedef __attribute__((ext_vector_type(4))) int   i32x4;
typedef __attribute__((ext_vector_type(4))) unsigned u32x4;
typedef signed char i8;

#define N_ROWS 32768
#define K_KEYS 4096
#define DDIM   1024
#define BM 32
#define BK 128
#define NBLK (K_KEYS / BK)   /* 32 */
#define SP 132               /* Sx u32 pitch */
#define SC2 (1.52587890625e-05f) /* 2^-16 */

__device__ __forceinline__ ushort f2bf(float f) {
    __hip_bfloat16 b = __float2bfloat16(f);
    return *(ushort*)&b;
}
__device__ __forceinline__ float bf2f(ushort u) {
    __hip_bfloat16 b = *(__hip_bfloat16*)&u;
    return __bfloat162float(b);
}
__device__ __forceinline__ int clampi(int x) { return x > 127 ? 127 : (x < -127 ? -127 : x); }

// B-side P1 mask: [KL,KH] byte pairs -> [KH,0], so qM2=[QH,QL] dotted with it
// yields exactly sum QH*KH (the P1 pass) with NO persistent masked-Q operand.
// kB is freshly loaded each gt, so this can't be hoisted into persistent regs.
__device__ __forceinline__ i32x4 mask_kh(i32x4 b) {
    u32x4 u = (u32x4)b;
    u = (u >> 8) & 0x00FF00FFu;
    return (i32x4)u;
}

// Pt swizzle (ushort units, 8-ushort granule XORed with row&7)
__device__ __forceinline__ int pidx(int r, int c_us) { return r * 128 + (c_us ^ ((r & 7) << 3)); }

// barrier that does NOT drain vmcnt: global prefetches stay in flight.
__device__ __forceinline__ void barrier_lgkm() {
    asm volatile("s_waitcnt lgkmcnt(0)" ::: "memory");
    __builtin_amdgcn_s_barrier();
    asm volatile("" ::: "memory");
}

// ---- prep: keys -> single K stream: [KL,KH] interleaved, tiles (g,m)=16 keys x 32 dims ----
__global__ void prep_kb(const float* __restrict__ keys, i8* __restrict__ sb) {
    int idx  = blockIdx.x * 256 + threadIdx.x;
    int lane = idx & 63, tile = idx >> 6;        // tile = g*32 + m
    int g = tile >> 5, m = tile & 31;
    int key = g * 16 + (lane & 15);
    int d0  = m * 32 + (lane >> 4) * 8;
    const float* s = keys + (size_t)key * DDIM + d0;
    union { i32x4 v; i8 b[16]; } u;
#pragma unroll
    for (int e = 0; e < 8; e++) {
        float q = s[e];
        int h = clampi((int)rintf(q * 16.f));
        int l = clampi((int)rintf((q - (float)h * 0.0625f) * 4096.f));
        u.b[2 * e]     = (i8)l;   // KL pairs with QH
        u.b[2 * e + 1] = (i8)h;   // KH pairs with QL (and with QH via mask_kh)
    }
    *(i32x4*)(sb + (size_t)tile * 1024 + lane * 16) = u.v;
}

// ---- prep: values fp32 [K][D] -> packed V^T bf16 fragment tiles ----
__global__ void prep_vt(const float* __restrict__ v, ushort* __restrict__ vt) {
    __shared__ float t[32][33];
    const int tk = blockIdx.x;
    const int td = blockIdx.y;
    const int tx = threadIdx.x & 31;
    const int ty = threadIdx.x >> 5;
#pragma unroll
    for (int r = 0; r < 4; r++) {
        int k = tk * 32 + ty + 8 * r;
        t[ty + 8 * r][tx] = v[(size_t)k * DDIM + td * 32 + tx];
    }
    __syncthreads();
    if (threadIdx.x < 128) {
        int s    = threadIdx.x >> 6;
        int lane = threadIdx.x & 63;
        int l16  = lane & 15, lq = lane >> 4;
        int dg   = td * 2 + s;
        int dl   = s * 16 + l16;
        bf16x8 o;
#pragma unroll
        for (int e = 0; e < 8; e++)
            o[e] = (short)f2bf(t[lq * 8 + e][dl]);
        *(bf16x8*)(vt + ((size_t)dg * 128 + tk) * 512 + lane * 8) = o;
    }
}

// Fused flash kernel, 16-WAVE (1024 threads), round-15 structure with the
// qP1z operand ELIMINATED (-16 persistent regs): P1 computed via per-gt
// B-side masking (mask_kh). Plus PV pa0/pa1 stagger (-8 peak regs).
// Goal: fit the 128-reg/wave budget with ZERO spill (round 15 was ~10 over:
// ~90MB spill writes + ~200MB spill reads per dispatch).
// Ledger: live-across-softmax state must not exceed round 15's set
// (rounds 10/11/12/16 all spilled by adding 16-48 regs there).
__launch_bounds__(1024, 4)
__global__ void attn_main(const float* __restrict__ z,
                          const i8* __restrict__ sb,
                          const ushort* __restrict__ vtp,
                          float* __restrict__ out) {
    __shared__ unsigned Sx[BM][SP];       // 16896 B, fixed-point 2^-16
    __shared__ ushort Pt2[2][BM * 128];   // 16384 B
    __shared__ float  m_s[BM], l_s[BM], sc_s[BM];

    const int tid  = threadIdx.x;
    const int wave = tid >> 6;            // 0..15
    const int lane = tid & 63;
    const int l16  = lane & 15;
    const int lq   = lane >> 4;
    const int row0 = blockIdx.x * BM;

    // ---- Q fragments for this wave's 64 dims, in registers ----
    // qM2[rg][m]: even byte QH, odd byte QL
    i32x4 qM2[2][2];
#pragma unroll
    for (int rg = 0; rg < 2; rg++) {
        int row = row0 + rg * 16 + l16;
        const float* zr = z + (size_t)row * DDIM + wave * 64;
#pragma unroll
        for (int m = 0; m < 2; m++) {
            union { i32x4 v; i8 b[16]; } u;
            const float* s = zr + m * 32 + lq * 8;
#pragma unroll
            for (int e = 0; e < 8; e++) {
                float q = s[e];
                int h = clampi((int)rintf(q * 16.f));
                int l = clampi((int)rintf((q - (float)h * 0.0625f) * 4096.f));
                u.b[2 * e]     = (i8)h;
                u.b[2 * e + 1] = (i8)l;
            }
            qM2[rg][m] = u.v;
        }
    }
    if (tid < BM) { m_s[tid] = -1e30f; l_s[tid] = 0.f; }
    for (int i = tid; i < BM * SP; i += 1024)
        ((unsigned*)Sx)[i] = 0u;
    __syncthreads();

    f32x4 Oacc[2][4];
#pragma unroll
    for (int mt = 0; mt < 2; mt++)
#pragma unroll
        for (int nt = 0; nt < 4; nt++)
            Oacc[mt][nt] = (f32x4){0.f, 0.f, 0.f, 0.f};

    // K stream: wave uses m-slices {2w, 2w+1} of each 16-key tile g
    const i8* sbB = sb + (size_t)wave * 2048 + lane * 16;
    // vt: wave owns dg = 4w..4w+3 (nt=0..3)
    const ushort* vtB = vtp + (size_t)wave * 262144 + lane * 8;

    i32x4 kB[2][2];
#define LOADKB(gg, buf)                                                        \
    do {                                                                       \
        const i8* _b = sbB + (size_t)(gg) * 32768;                             \
        kB[buf][0] = *(const i32x4*)_b;                                        \
        kB[buf][1] = *(const i32x4*)(_b + 1024);                               \
    } while (0)

    LOADKB(0, 0);

    for (int b = 0; b < NBLK; b++) {
        // ---- QK^T: per key-tile gt (16 keys), 8 int8 MFMAs over 64 dims ----
#pragma unroll
        for (int gt = 0; gt < 8; gt++) {
            const int cb = gt & 1, nb2 = cb ^ 1;
            if (gt < 7) {
                LOADKB(8 * b + gt + 1, nb2);
            } else {
                int gn = (b + 1 < NBLK) ? 8 * (b + 1) : 8 * b;
                LOADKB(gn, nb2);
            }
            i32x4 p1a = {0,0,0,0}, p1b = {0,0,0,0};
            i32x4 m2a = {0,0,0,0}, m2b = {0,0,0,0};
            // cross terms (QH*KL + QL*KH), m = 0,1
            m2a = __builtin_amdgcn_mfma_i32_16x16x64_i8(qM2[0][0], kB[cb][0], m2a, 0, 0, 0);
            m2b = __builtin_amdgcn_mfma_i32_16x16x64_i8(qM2[1][0], kB[cb][0], m2b, 0, 0, 0);
            m2a = __builtin_amdgcn_mfma_i32_16x16x64_i8(qM2[0][1], kB[cb][1], m2a, 0, 0, 0);
            m2b = __builtin_amdgcn_mfma_i32_16x16x64_i8(qM2[1][1], kB[cb][1], m2b, 0, 0, 0);
            // P1 (QH*KH) via B-side mask — no persistent masked operand
            {
                i32x4 kp0 = mask_kh(kB[cb][0]);
                i32x4 kp1 = mask_kh(kB[cb][1]);
                p1a = __builtin_amdgcn_mfma_i32_16x16x64_i8(qM2[0][0], kp0, p1a, 0, 0, 0);
                p1b = __builtin_amdgcn_mfma_i32_16x16x64_i8(qM2[1][0], kp0, p1b, 0, 0, 0);
                p1a = __builtin_amdgcn_mfma_i32_16x16x64_i8(qM2[0][1], kp1, p1a, 0, 0, 0);
                p1b = __builtin_amdgcn_mfma_i32_16x16x64_i8(qM2[1][1], kp1, p1b, 0, 0, 0);
            }

            const int col = gt * 16 + l16;
#pragma unroll
            for (int r = 0; r < 4; r++) {
                int fa = p1a[r] * 256 + m2a[r];
                int fb = p1b[r] * 256 + m2b[r];
                atomicAdd(&Sx[lq * 4 + r][col],      (unsigned)fa);
                atomicAdd(&Sx[16 + lq * 4 + r][col], (unsigned)fb);
            }
        }

        // vt kc=0 prefetch (single buffer): lands during softmax
        bf16x8 vbuf[4];
        const ushort* vtI = vtB + (size_t)b * 2048;
#pragma unroll
        for (int nt = 0; nt < 4; nt++)
            vbuf[nt] = *(const bf16x8*)(vtI + nt * 65536);

        barrier_lgkm();

        // ---- softmax: thread (row, c0) owns cols [4c0, 4c0+4), 32 threads/row ----
        {
            const int row = tid >> 5;
            const int c0  = tid & 31;
            i32x4 w0 = *(const i32x4*)&Sx[row][4 * c0];
            *(i32x4*)&Sx[row][4 * c0] = (i32x4){0,0,0,0};   // zero for next iter
            float sv[4];
#pragma unroll
            for (int j = 0; j < 4; j++)
                sv[j] = (float)w0[j] * SC2;
            float mloc = fmaxf(fmaxf(sv[0], sv[1]), fmaxf(sv[2], sv[3]));
#pragma unroll
            for (int off = 16; off >= 1; off >>= 1)
                mloc = fmaxf(mloc, __shfl_xor(mloc, off));
            float m_old = m_s[row];
            float m_new = fmaxf(m_old, mloc);
            float psum = 0.f;
            ushort pb[4];
#pragma unroll
            for (int j = 0; j < 4; j++) {
                float p = __expf(sv[j] - m_new);
                psum += p;
                pb[j] = f2bf(p);
            }
            *(ushort4*)&Pt2[b & 1][pidx(row, 4 * c0)] = make_ushort4(pb[0], pb[1], pb[2], pb[3]);
#pragma unroll
            for (int off = 16; off >= 1; off >>= 1)
                psum += __shfl_xor(psum, off);
            if (c0 == 0) {
                float sc = __expf(m_old - m_new);
                l_s[row] = l_s[row] * sc + psum;
                m_s[row] = m_new;
                sc_s[row] = sc;
            }
        }
        barrier_lgkm();

        // ---- rescale O (exact skip when all sc==1), then PV ----
        {
            float sc0[4], sc1[4];
#pragma unroll
            for (int r = 0; r < 4; r++) {
                sc0[r] = sc_s[lq * 4 + r];
                sc1[r] = sc_s[16 + lq * 4 + r];
            }
            bool need = (sc0[0] != 1.f) || (sc0[1] != 1.f) || (sc0[2] != 1.f) || (sc0[3] != 1.f) ||
                        (sc1[0] != 1.f) || (sc1[1] != 1.f) || (sc1[2] != 1.f) || (sc1[3] != 1.f);
            if (__any(need)) {
#pragma unroll
                for (int nt = 0; nt < 4; nt++)
#pragma unroll
                    for (int r = 0; r < 4; r++) {
                        Oacc[0][nt][r] *= sc0[r];
                        Oacc[1][nt][r] *= sc1[r];
                    }
            }
        }

        const ushort* PtC = &Pt2[b & 1][0];
#pragma unroll
        for (int kc = 0; kc < 4; kc++) {
            // staggered: pa0 then pa1 (one pa live at a time)
            {
                bf16x8 pa0 = *(const bf16x8*)&PtC[pidx(l16, kc * 32 + lq * 8)];
#pragma unroll
                for (int nt = 0; nt < 4; nt++)
                    Oacc[0][nt] = __builtin_amdgcn_mfma_f32_16x16x32_bf16(pa0, vbuf[nt], Oacc[0][nt], 0, 0, 0);
            }
            {
                bf16x8 pa1 = *(const bf16x8*)&PtC[pidx(16 + l16, kc * 32 + lq * 8)];
#pragma unroll
                for (int nt = 0; nt < 4; nt++)
                    Oacc[1][nt] = __builtin_amdgcn_mfma_f32_16x16x32_bf16(pa1, vbuf[nt], Oacc[1][nt], 0, 0, 0);
            }
            // sequential reload of the single buffer with kc+1 (after MFMAs issue)
            if (kc < 3) {
#pragma unroll
                for (int nt = 0; nt < 4; nt++)
                    vbuf[nt] = *(const bf16x8*)(vtI + nt * 65536 + (kc + 1) * 512);
            }
        }
    }
    __syncthreads();

    // ---- epilogue: normalize by l and store ----
    float li0[4], li1[4];
#pragma unroll
    for (int r = 0; r < 4; r++) {
        li0[r] = 1.f / l_s[lq * 4 + r];
        li1[r] = 1.f / l_s[16 + lq * 4 + r];
    }
#pragma unroll
    for (int nt = 0; nt < 4; nt++) {
#pragma unroll
        for (int r = 0; r < 4; r++) {
            int col = wave * 64 + nt * 16 + l16;
            int rowA = row0 + lq * 4 + r;
            out[(size_t)rowA * DDIM + col]        = Oacc[0][nt][r] * li0[r];
            out[(size_t)(rowA + 16) * DDIM + col] = Oacc[1][nt][r] * li1[r];
        }
    }
}

extern "C" void kernel_launch(void* const* d_in, const int* in_sizes, int n_in,
                              void* d_out, int out_size, void* d_ws, size_t ws_size,
                              hipStream_t stream) {
    const float* z    = (const float*)d_in[0];
    const float* keys = (const float*)d_in[1];
    const float* vals = (const float*)d_in[2];
    float* outp = (float*)d_out;

    i8* sb = (i8*)d_ws;                                    // 8 MB (merged [KL,KH] tiles)
    ushort* vtw = (ushort*)(sb + (size_t)8 * 1024 * 1024); // 8 MB (V^T bf16 tiles)

    prep_kb<<<2048, 256, 0, stream>>>(keys, sb);
    prep_vt<<<dim3(K_KEYS / 32, DDIM / 32), 256, 0, stream>>>(vals, vtw);
    attn_main<<<N_ROWS / BM, 1024, 0, stream>>>(z, sb, vtw, outp);
}

// Round 18
// 915.811 us; speedup vs baseline: 1.2555x; 1.0143x over previous
//
#include <hip/hip_runtime.h>
#include <hip/hip_bf16.h>

typedef __attribute__((ext_vector_type(8))) short bf16x8;
typedef __attribute__((ext_vector_type(4))) float f32x4;
typedef __attribute__((ext_vector_type(4))) int   i32x4;
typedef __attribute__((ext_vector_type(4))) unsigned u32x4;
typedef signed char i8;

#define N_ROWS 32768
#define K_KEYS 4096
#define DDIM   1024
#define BM 32
#define BK 256
#define NBLK (K_KEYS / BK)   /* 16 */
#define SP 260               /* Sx u32 pitch: 260%32==4 -> same 2-way-free banks as 132 */
#define SC2 (1.52587890625e-05f) /* 2^-16 */

__device__ __forceinline__ ushort f2bf(float f) {
    __hip_bfloat16 b = __float2bfloat16(f);
    return *(ushort*)&b;
}
__device__ __forceinline__ float bf2f(ushort u) {
    __hip_bfloat16 b = *(__hip_bfloat16*)&u;
    return __bfloat162float(b);
}
__device__ __forceinline__ int clampi(int x) { return x > 127 ? 127 : (x < -127 ? -127 : x); }

// B-side P1 mask: [KL,KH] byte pairs -> [KH,0]; qM2=[QH,QL] dotted with it
// gives exactly sum QH*KH. kB is freshly loaded each gt -> no persistent regs.
__device__ __forceinline__ i32x4 mask_kh(i32x4 b) {
    u32x4 u = (u32x4)b;
    u = (u >> 8) & 0x00FF00FFu;
    return (i32x4)u;
}

// Pt swizzle (ushort units, pitch 256, 8-ushort granule XORed with row&7)
__device__ __forceinline__ int pidx(int r, int c_us) { return r * 256 + (c_us ^ ((r & 7) << 3)); }

// barrier that does NOT drain vmcnt: global prefetches stay in flight.
__device__ __forceinline__ void barrier_lgkm() {
    asm volatile("s_waitcnt lgkmcnt(0)" ::: "memory");
    __builtin_amdgcn_s_barrier();
    asm volatile("" ::: "memory");
}

// ---- prep: keys -> single K stream: [KL,KH] interleaved, tiles (g,m)=16 keys x 32 dims ----
__global__ void prep_kb(const float* __restrict__ keys, i8* __restrict__ sb) {
    int idx  = blockIdx.x * 256 + threadIdx.x;
    int lane = idx & 63, tile = idx >> 6;        // tile = g*32 + m
    int g = tile >> 5, m = tile & 31;
    int key = g * 16 + (lane & 15);
    int d0  = m * 32 + (lane >> 4) * 8;
    const float* s = keys + (size_t)key * DDIM + d0;
    union { i32x4 v; i8 b[16]; } u;
#pragma unroll
    for (int e = 0; e < 8; e++) {
        float q = s[e];
        int h = clampi((int)rintf(q * 16.f));
        int l = clampi((int)rintf((q - (float)h * 0.0625f) * 4096.f));
        u.b[2 * e]     = (i8)l;   // KL pairs with QH
        u.b[2 * e + 1] = (i8)h;   // KH pairs with QL (and with QH via mask_kh)
    }
    *(i32x4*)(sb + (size_t)tile * 1024 + lane * 16) = u.v;
}

// ---- prep: values fp32 [K][D] -> packed V^T bf16 fragment tiles ----
__global__ void prep_vt(const float* __restrict__ v, ushort* __restrict__ vt) {
    __shared__ float t[32][33];
    const int tk = blockIdx.x;
    const int td = blockIdx.y;
    const int tx = threadIdx.x & 31;
    const int ty = threadIdx.x >> 5;
#pragma unroll
    for (int r = 0; r < 4; r++) {
        int k = tk * 32 + ty + 8 * r;
        t[ty + 8 * r][tx] = v[(size_t)k * DDIM + td * 32 + tx];
    }
    __syncthreads();
    if (threadIdx.x < 128) {
        int s    = threadIdx.x >> 6;
        int lane = threadIdx.x & 63;
        int l16  = lane & 15, lq = lane >> 4;
        int dg   = td * 2 + s;
        int dl   = s * 16 + l16;
        bf16x8 o;
#pragma unroll
        for (int e = 0; e < 8; e++)
            o[e] = (short)f2bf(t[lq * 8 + e][dl]);
        *(bf16x8*)(vt + ((size_t)dg * 128 + tk) * 512 + lane * 8) = o;
    }
}

// Fused flash kernel, 16-WAVE (1024 threads), round-17 structure with
// BK=256 (16 K-blocks instead of 32): halves all per-phase fixed costs
// (softmax VALU, 10-shfl reductions, O-rescale, barrier drains) while QK/PV
// MFMA and byte streams are unchanged. Register footprint identical to
// round 17 (ledger: live-across-softmax set unchanged -> no new spill).
__launch_bounds__(1024, 4)
__global__ void attn_main(const float* __restrict__ z,
                          const i8* __restrict__ sb,
                          const ushort* __restrict__ vtp,
                          float* __restrict__ out) {
    __shared__ unsigned Sx[BM][SP];       // 33280 B, fixed-point 2^-16
    __shared__ ushort Pt2[2][BM * 256];   // 32768 B
    __shared__ float  m_s[BM], l_s[BM], sc_s[BM];

    const int tid  = threadIdx.x;
    const int wave = tid >> 6;            // 0..15
    const int lane = tid & 63;
    const int l16  = lane & 15;
    const int lq   = lane >> 4;
    const int row0 = blockIdx.x * BM;

    // ---- Q fragments for this wave's 64 dims, in registers ----
    // qM2[rg][m]: even byte QH, odd byte QL
    i32x4 qM2[2][2];
#pragma unroll
    for (int rg = 0; rg < 2; rg++) {
        int row = row0 + rg * 16 + l16;
        const float* zr = z + (size_t)row * DDIM + wave * 64;
#pragma unroll
        for (int m = 0; m < 2; m++) {
            union { i32x4 v; i8 b[16]; } u;
            const float* s = zr + m * 32 + lq * 8;
#pragma unroll
            for (int e = 0; e < 8; e++) {
                float q = s[e];
                int h = clampi((int)rintf(q * 16.f));
                int l = clampi((int)rintf((q - (float)h * 0.0625f) * 4096.f));
                u.b[2 * e]     = (i8)h;
                u.b[2 * e + 1] = (i8)l;
            }
            qM2[rg][m] = u.v;
        }
    }
    if (tid < BM) { m_s[tid] = -1e30f; l_s[tid] = 0.f; }
    for (int i = tid; i < BM * SP; i += 1024)
        ((unsigned*)Sx)[i] = 0u;
    __syncthreads();

    f32x4 Oacc[2][4];
#pragma unroll
    for (int mt = 0; mt < 2; mt++)
#pragma unroll
        for (int nt = 0; nt < 4; nt++)
            Oacc[mt][nt] = (f32x4){0.f, 0.f, 0.f, 0.f};

    // K stream: wave uses m-slices {2w, 2w+1} of each 16-key tile g
    const i8* sbB = sb + (size_t)wave * 2048 + lane * 16;
    // vt: wave owns dg = 4w..4w+3 (nt=0..3)
    const ushort* vtB = vtp + (size_t)wave * 262144 + lane * 8;

    i32x4 kB[2][2];
#define LOADKB(gg, buf)                                                        \
    do {                                                                       \
        const i8* _b = sbB + (size_t)(gg) * 32768;                             \
        kB[buf][0] = *(const i32x4*)_b;                                        \
        kB[buf][1] = *(const i32x4*)(_b + 1024);                               \
    } while (0)

    LOADKB(0, 0);

    for (int b = 0; b < NBLK; b++) {
        // ---- QK^T: per key-tile gt (16 keys), 8 int8 MFMAs over 64 dims ----
#pragma unroll
        for (int gt = 0; gt < 16; gt++) {
            const int cb = gt & 1, nb2 = cb ^ 1;
            if (gt < 15) {
                LOADKB(16 * b + gt + 1, nb2);
            } else {
                int gn = (b + 1 < NBLK) ? 16 * (b + 1) : 16 * b;
                LOADKB(gn, nb2);
            }
            i32x4 p1a = {0,0,0,0}, p1b = {0,0,0,0};
            i32x4 m2a = {0,0,0,0}, m2b = {0,0,0,0};
            // cross terms (QH*KL + QL*KH), m = 0,1
            m2a = __builtin_amdgcn_mfma_i32_16x16x64_i8(qM2[0][0], kB[cb][0], m2a, 0, 0, 0);
            m2b = __builtin_amdgcn_mfma_i32_16x16x64_i8(qM2[1][0], kB[cb][0], m2b, 0, 0, 0);
            m2a = __builtin_amdgcn_mfma_i32_16x16x64_i8(qM2[0][1], kB[cb][1], m2a, 0, 0, 0);
            m2b = __builtin_amdgcn_mfma_i32_16x16x64_i8(qM2[1][1], kB[cb][1], m2b, 0, 0, 0);
            // P1 (QH*KH) via B-side mask — no persistent masked operand
            {
                i32x4 kp0 = mask_kh(kB[cb][0]);
                i32x4 kp1 = mask_kh(kB[cb][1]);
                p1a = __builtin_amdgcn_mfma_i32_16x16x64_i8(qM2[0][0], kp0, p1a, 0, 0, 0);
                p1b = __builtin_amdgcn_mfma_i32_16x16x64_i8(qM2[1][0], kp0, p1b, 0, 0, 0);
                p1a = __builtin_amdgcn_mfma_i32_16x16x64_i8(qM2[0][1], kp1, p1a, 0, 0, 0);
                p1b = __builtin_amdgcn_mfma_i32_16x16x64_i8(qM2[1][1], kp1, p1b, 0, 0, 0);
            }

            const int col = gt * 16 + l16;
#pragma unroll
            for (int r = 0; r < 4; r++) {
                int fa = p1a[r] * 256 + m2a[r];
                int fb = p1b[r] * 256 + m2b[r];
                atomicAdd(&Sx[lq * 4 + r][col],      (unsigned)fa);
                atomicAdd(&Sx[16 + lq * 4 + r][col], (unsigned)fb);
            }
        }

        // vt kc=0 prefetch (single buffer): lands during softmax
        bf16x8 vbuf[4];
        const ushort* vtI = vtB + (size_t)b * 4096;
#pragma unroll
        for (int nt = 0; nt < 4; nt++)
            vbuf[nt] = *(const bf16x8*)(vtI + nt * 65536);

        barrier_lgkm();

        // ---- softmax: thread (row, c0) owns cols [8c0, 8c0+8), 32 threads/row ----
        {
            const int row = tid >> 5;
            const int c0  = tid & 31;
            i32x4 w0 = *(const i32x4*)&Sx[row][8 * c0];
            i32x4 w1 = *(const i32x4*)&Sx[row][8 * c0 + 4];
            *(i32x4*)&Sx[row][8 * c0]     = (i32x4){0,0,0,0};   // zero for next iter
            *(i32x4*)&Sx[row][8 * c0 + 4] = (i32x4){0,0,0,0};
            float sv[8];
#pragma unroll
            for (int j = 0; j < 4; j++) {
                sv[j]     = (float)w0[j] * SC2;
                sv[4 + j] = (float)w1[j] * SC2;
            }
            float mloc = sv[0];
#pragma unroll
            for (int j = 1; j < 8; j++) mloc = fmaxf(mloc, sv[j]);
#pragma unroll
            for (int off = 16; off >= 1; off >>= 1)
                mloc = fmaxf(mloc, __shfl_xor(mloc, off));
            float m_old = m_s[row];
            float m_new = fmaxf(m_old, mloc);
            float psum = 0.f;
            bf16x8 pb;
#pragma unroll
            for (int j = 0; j < 8; j++) {
                float p = __expf(sv[j] - m_new);
                psum += p;
                pb[j] = (short)f2bf(p);
            }
            *(bf16x8*)&Pt2[b & 1][pidx(row, 8 * c0)] = pb;
#pragma unroll
            for (int off = 16; off >= 1; off >>= 1)
                psum += __shfl_xor(psum, off);
            if (c0 == 0) {
                float sc = __expf(m_old - m_new);
                l_s[row] = l_s[row] * sc + psum;
                m_s[row] = m_new;
                sc_s[row] = sc;
            }
        }
        barrier_lgkm();

        // ---- rescale O (exact skip when all sc==1), then PV over 256 keys ----
        {
            float sc0[4], sc1[4];
#pragma unroll
            for (int r = 0; r < 4; r++) {
                sc0[r] = sc_s[lq * 4 + r];
                sc1[r] = sc_s[16 + lq * 4 + r];
            }
            bool need = (sc0[0] != 1.f) || (sc0[1] != 1.f) || (sc0[2] != 1.f) || (sc0[3] != 1.f) ||
                        (sc1[0] != 1.f) || (sc1[1] != 1.f) || (sc1[2] != 1.f) || (sc1[3] != 1.f);
            if (__any(need)) {
#pragma unroll
                for (int nt = 0; nt < 4; nt++)
#pragma unroll
                    for (int r = 0; r < 4; r++) {
                        Oacc[0][nt][r] *= sc0[r];
                        Oacc[1][nt][r] *= sc1[r];
                    }
            }
        }

        const ushort* PtC = &Pt2[b & 1][0];
#pragma unroll
        for (int kc = 0; kc < 8; kc++) {
            // staggered: pa0 then pa1 (one pa live at a time)
            {
                bf16x8 pa0 = *(const bf16x8*)&PtC[pidx(l16, kc * 32 + lq * 8)];
#pragma unroll
                for (int nt = 0; nt < 4; nt++)
                    Oacc[0][nt] = __builtin_amdgcn_mfma_f32_16x16x32_bf16(pa0, vbuf[nt], Oacc[0][nt], 0, 0, 0);
            }
            {
                bf16x8 pa1 = *(const bf16x8*)&PtC[pidx(16 + l16, kc * 32 + lq * 8)];
#pragma unroll
                for (int nt = 0; nt < 4; nt++)
                    Oacc[1][nt] = __builtin_amdgcn_mfma_f32_16x16x32_bf16(pa1, vbuf[nt], Oacc[1][nt], 0, 0, 0);
            }
            // sequential reload of the single buffer with kc+1 (after MFMAs issue)
            if (kc < 7) {
#pragma unroll
                for (int nt = 0; nt < 4; nt++)
                    vbuf[nt] = *(const bf16x8*)(vtI + nt * 65536 + (kc + 1) * 512);
            }
        }
    }
    __syncthreads();

    // ---- epilogue: normalize by l and store ----
    float li0[4], li1[4];
#pragma unroll
    for (int r = 0; r < 4; r++) {
        li0[r] = 1.f / l_s[lq * 4 + r];
        li1[r] = 1.f / l_s[16 + lq * 4 + r];
    }
#pragma unroll
    for (int nt = 0; nt < 4; nt++) {
#pragma unroll
        for (int r = 0; r < 4; r++) {
            int col = wave * 64 + nt * 16 + l16;
            int rowA = row0 + lq * 4 + r;
            out[(size_t)rowA * DDIM + col]        = Oacc[0][nt][r] * li0[r];
            out[(size_t)(rowA + 16) * DDIM + col] = Oacc[1][nt][r] * li1[r];
        }
    }
}

extern "C" void kernel_launch(void* const* d_in, const int* in_sizes, int n_in,
                              void* d_out, int out_size, void* d_ws, size_t ws_size,
                              hipStream_t stream) {
    const float* z    = (const float*)d_in[0];
    const float* keys = (const float*)d_in[1];
    const float* vals = (const float*)d_in[2];
    float* outp = (float*)d_out;

    i8* sb = (i8*)d_ws;                                    // 8 MB (merged [KL,KH] tiles)
    ushort* vtw = (ushort*)(sb + (size_t)8 * 1024 * 1024); // 8 MB (V^T bf16 tiles)

    prep_kb<<<2048, 256, 0, stream>>>(keys, sb);
    prep_vt<<<dim3(K_KEYS / 32, DDIM / 32), 256, 0, stream>>>(vals, vtw);
    attn_main<<<N_ROWS / BM, 1024, 0, stream>>>(z, sb, vtw, outp);
}